// Round 5
// baseline (558.972 us; speedup 1.0000x reference)
//
#include <hip/hip_runtime.h>
#include <math.h>

// GAT 2-layer fp32.
// R5: kP1 binning uses packed 32-bit records ((dst&1023)<<22|src) with stride-33
//     LDS staging (bank-conflict-free flush). tf1 fused into agg8 epilogue via
//     shfl-broadcast + LDS-staged W1 (no hb round-trip).

#define CAPS 32     // staged records per bucket before flush
#define STRIDE 33   // padded stage stride (words) -> conflict-free flush
#define NBMAX 128   // max dst buckets (N <= 131072; also src < 2^22 for packing)

__device__ __forceinline__ float lrelu(float v) { return v >= 0.f ? v : 0.2f * v; }
__device__ __forceinline__ float eluf(float v)  { return v > 0.f ? v : expm1f(v); }

// ---------------- transform body: 8 waves/block, 8 nodes/wave, lane = col ----
template<int K, int HEADS>
__device__ __forceinline__ void tf_body8(
    int tfb, const float* __restrict__ xin, const float* __restrict__ W,
    const float* __restrict__ attS, const float* __restrict__ attD,
    int N, float* __restrict__ xw, float* __restrict__ as, float* __restrict__ ad,
    float* Wl)
{
    const float4* Wv = (const float4*)W;
    float4* Wlv = (float4*)Wl;
    for (int i = threadIdx.x; i < K * 16; i += 512) Wlv[i] = Wv[i];
    __syncthreads();
    int wave = threadIdx.x >> 6;
    int lane = threadIdx.x & 63;
    int n0 = tfb * 64 + wave * 8;
    if (n0 >= N) return;
    int cnt = min(8, N - n0);
    const float4* xp[8];
    #pragma unroll
    for (int j = 0; j < 8; j++)
        xp[j] = (const float4*)(xin + (size_t)(n0 + (j < cnt ? j : 0)) * K);
    float acc[8] = {0.f,0.f,0.f,0.f,0.f,0.f,0.f,0.f};
    #pragma unroll 2
    for (int k4 = 0; k4 < K / 4; k4++) {
        float4 xv[8];
        #pragma unroll
        for (int j = 0; j < 8; j++) xv[j] = xp[j][k4];
        int kb = k4 * 256 + lane;
        float w0 = Wl[kb], w1 = Wl[kb + 64], w2 = Wl[kb + 128], w3 = Wl[kb + 192];
        #pragma unroll
        for (int j = 0; j < 8; j++) {
            acc[j] = fmaf(xv[j].x, w0, acc[j]);
            acc[j] = fmaf(xv[j].y, w1, acc[j]);
            acc[j] = fmaf(xv[j].z, w2, acc[j]);
            acc[j] = fmaf(xv[j].w, w3, acc[j]);
        }
    }
    float aSl = attS[lane], aDl = attD[lane];
    #pragma unroll
    for (int j = 0; j < 8; j++) {
        if (j < cnt) {
            int n = n0 + j;
            xw[(size_t)n * 64 + lane] = acc[j];
            float ps = acc[j] * aSl, pd = acc[j] * aDl;
            if (HEADS == 8) {
                ps += __shfl_xor(ps, 1, 64); pd += __shfl_xor(pd, 1, 64);
                ps += __shfl_xor(ps, 2, 64); pd += __shfl_xor(pd, 2, 64);
                ps += __shfl_xor(ps, 4, 64); pd += __shfl_xor(pd, 4, 64);
                if ((lane & 7) == 0) {
                    as[(size_t)n * 8 + (lane >> 3)] = ps;
                    ad[(size_t)n * 8 + (lane >> 3)] = pd;
                }
            } else {
                #pragma unroll
                for (int off = 1; off < 64; off <<= 1) {
                    ps += __shfl_xor(ps, off, 64);
                    pd += __shfl_xor(pd, off, 64);
                }
                if (lane == 0) { as[n] = ps; ad[n] = pd; }
            }
        }
    }
}

// ---------------- fused: phase1 binning || tf0 ----------------
__global__ __launch_bounds__(512, 4) void kP1(
    const float* __restrict__ x, const float* __restrict__ W0,
    const float* __restrict__ aS, const float* __restrict__ aD,
    int N, float* __restrict__ xw, float* __restrict__ as, float* __restrict__ ad,
    int tfBlocks,
    const int* __restrict__ src, const int* __restrict__ dst, int E,
    int p1Blocks, int perBlock,
    unsigned* __restrict__ bucketBuf, int* __restrict__ gcur, int NB, int cap)
{
    __shared__ __align__(16) char smem[128 * 64 * 4];   // 32 KB union
    int b = blockIdx.x;
    int T = tfBlocks + p1Blocks;
    int lo = (int)((long long)b * tfBlocks / T);
    int hi = (int)((long long)(b + 1) * tfBlocks / T);
    if (hi > lo) {
        tf_body8<128, 8>(lo, x, W0, aS, aD, N, xw, as, ad, (float*)smem);
    } else {
        int pb = b - hi;
        unsigned* stage = (unsigned*)smem;                       // NBMAX*STRIDE words
        int* scnt = (int*)(smem + NBMAX * STRIDE * 4);           // NBMAX words
        int tid = threadIdx.x;
        for (int i = tid; i < NB; i += 512) scnt[i] = 0;
        __syncthreads();
        int e0 = pb * perBlock, e1 = min(E, e0 + perBlock);
        for (int base = e0; base < e1; base += 512) {
            int i = base + tid;
            if (i < e1) {
                int d = dst[i], s = src[i];
                int bk = d >> 10;
                unsigned rec = ((unsigned)(d & 1023) << 22) | (unsigned)s;
                int pos = atomicAdd(&scnt[bk], 1);
                if (pos < CAPS) {
                    stage[bk * STRIDE + pos] = rec;
                } else {
                    int g = atomicAdd(&gcur[bk], 1);
                    bucketBuf[(size_t)bk * cap + g] = rec;
                }
            }
            __syncthreads();
            if (tid < NB) {
                int n = min(scnt[tid], CAPS);
                int g16 = n & ~15;
                if (g16) {
                    int gb = atomicAdd(&gcur[tid], g16);
                    unsigned* gp = &bucketBuf[(size_t)tid * cap + gb];
                    for (int j = 0; j < g16; j++) gp[j] = stage[tid * STRIDE + j];
                    for (int j = 0; j < n - g16; j++)
                        stage[tid * STRIDE + j] = stage[tid * STRIDE + g16 + j];
                    scnt[tid] = n - g16;
                } else {
                    scnt[tid] = n;
                }
            }
            __syncthreads();
        }
        if (tid < NB) {
            int n = scnt[tid];
            if (n > 0) {
                int gb = atomicAdd(&gcur[tid], n);
                unsigned* gp = &bucketBuf[(size_t)tid * cap + gb];
                for (int j = 0; j < n; j++) gp[j] = stage[tid * STRIDE + j];
            }
        }
    }
}

// ---------------- phase2: per-bucket CSR build ----------------
__global__ __launch_bounds__(256) void kP2(
    const unsigned* __restrict__ bucketBuf, const int* __restrict__ gcur,
    int NB, int cap, int N, int* __restrict__ row, int* __restrict__ adj)
{
    __shared__ int deg[1024];
    __shared__ int curl[1024];
    __shared__ int sc[256];
    int b = blockIdx.x, tid = threadIdx.x;
    int lo = b << 10;
    int hi = min(N, lo + 1024);
    int cnt = hi - lo;
    int size = min(gcur[b], cap);
    sc[tid] = (tid < b) ? gcur[tid] : 0;
    __syncthreads();
    for (int off = 128; off > 0; off >>= 1) {
        if (tid < off) sc[tid] += sc[tid + off];
        __syncthreads();
    }
    int bbase = sc[0];
    __syncthreads();
    for (int i = tid; i < 1024; i += 256) deg[i] = 0;
    __syncthreads();
    const unsigned* buf = bucketBuf + (size_t)b * cap;
    for (int e = tid; e < size; e += 256) atomicAdd(&deg[buf[e] >> 22], 1);
    __syncthreads();
    int dv[4]; int s = 0;
    #pragma unroll
    for (int j = 0; j < 4; j++) { dv[j] = deg[tid * 4 + j]; s += dv[j]; }
    sc[tid] = s; __syncthreads();
    for (int off = 1; off < 256; off <<= 1) {
        int xv = (tid >= off) ? sc[tid - off] : 0;
        __syncthreads();
        sc[tid] += xv;
        __syncthreads();
    }
    int o = (tid ? sc[tid - 1] : 0);
    #pragma unroll
    for (int j = 0; j < 4; j++) {
        int loc = tid * 4 + j;
        curl[loc] = o;
        if (loc < cnt) row[lo + loc] = bbase + o;
        o += dv[j];
    }
    if (b == NB - 1 && tid == 0) row[N] = bbase + size;
    __syncthreads();
    for (int e = tid; e < size; e += 256) {
        unsigned r = buf[e];
        int l = r >> 22;
        int p = atomicAdd(&curl[l], 1);
        adj[bbase + p] = (int)(r & 0x3FFFFF);
    }
}

// ---------------- layer0 aggregation + fused layer1 transform ----------------
__global__ __launch_bounds__(256) void k_agg8_tf1(
    const float* __restrict__ xw, const float* __restrict__ as, const float* __restrict__ ad,
    const int* __restrict__ row, const int* __restrict__ adj,
    const float* __restrict__ bias, const float* __restrict__ W1,
    const float* __restrict__ aS1, const float* __restrict__ aD1,
    int N, float* __restrict__ hw, float* __restrict__ as1, float* __restrict__ ad1)
{
    __shared__ float Wl[64 * 64];
    {
        const float4* Wv = (const float4*)W1;
        float4* Wlv = (float4*)Wl;
        for (int i = threadIdx.x; i < 1024; i += 256) Wlv[i] = Wv[i];
    }
    __syncthreads();
    int n = (blockIdx.x * 256 + threadIdx.x) >> 6;
    int lane = threadIdx.x & 63;
    if (n >= N) return;
    int rs = row[n], re = row[n + 1];
    int hh = lane & 7;
    int e8 = lane >> 3;
    float adv = ad[(size_t)n * 8 + hh];
    float shift = lrelu(as[(size_t)n * 8 + hh] + adv);
    float dsum = 0.f;
    for (int j = rs; j < re; j += 8) {
        int jj = j + e8;
        bool v = jj < re;
        int s = adj[v ? jj : rs];
        float e = lrelu(as[(size_t)s * 8 + hh] + adv);
        float p = __expf(e - shift);
        dsum += v ? p : 0.f;
    }
    dsum += __shfl_xor(dsum, 8, 64);
    dsum += __shfl_xor(dsum, 16, 64);
    dsum += __shfl_xor(dsum, 32, 64);
    float denom = 1.f + dsum;
    int hb = lane >> 3;
    float advB   = __shfl(adv, hb, 64);
    float shiftB = __shfl(shift, hb, 64);
    float denomB = __shfl(denom, hb, 64);
    float acc = xw[(size_t)n * 64 + lane];
    for (int j = rs; j < re; j += 4) {
        bool v1 = j + 1 < re, v2 = j + 2 < re, v3 = j + 3 < re;
        int s0 = adj[j];
        int s1 = v1 ? adj[j + 1] : s0;
        int s2 = v2 ? adj[j + 2] : s0;
        int s3 = v3 ? adj[j + 3] : s0;
        float e0 = lrelu(as[(size_t)s0 * 8 + hb] + advB);
        float e1 = lrelu(as[(size_t)s1 * 8 + hb] + advB);
        float e2 = lrelu(as[(size_t)s2 * 8 + hb] + advB);
        float e3 = lrelu(as[(size_t)s3 * 8 + hb] + advB);
        float w0 = __expf(e0 - shiftB);
        float w1 = v1 ? __expf(e1 - shiftB) : 0.f;
        float w2 = v2 ? __expf(e2 - shiftB) : 0.f;
        float w3 = v3 ? __expf(e3 - shiftB) : 0.f;
        acc = fmaf(w0, xw[(size_t)s0 * 64 + lane], acc);
        acc = fmaf(w1, xw[(size_t)s1 * 64 + lane], acc);
        acc = fmaf(w2, xw[(size_t)s2 * 64 + lane], acc);
        acc = fmaf(w3, xw[(size_t)s3 * 64 + lane], acc);
    }
    float h = eluf(acc / denomB + bias[lane]);
    // ---- fused tf1: hw[n][lane] = sum_k h_k * W1[k][lane] ----
    float a1 = 0.f;
    #pragma unroll 16
    for (int k = 0; k < 64; k++) {
        float hk = __shfl(h, k, 64);
        a1 = fmaf(hk, Wl[k * 64 + lane], a1);
    }
    hw[(size_t)n * 64 + lane] = a1;
    float ps = a1 * aS1[lane], pd = a1 * aD1[lane];
    #pragma unroll
    for (int off = 1; off < 64; off <<= 1) {
        ps += __shfl_xor(ps, off, 64);
        pd += __shfl_xor(pd, off, 64);
    }
    if (lane == 0) { as1[n] = ps; ad1[n] = pd; }
}

// ---------------- layer1 aggregation ----------------
__global__ __launch_bounds__(256) void k_agg1(
    const float* __restrict__ hw, const float* __restrict__ as, const float* __restrict__ ad,
    const int* __restrict__ row, const int* __restrict__ adj,
    const float* __restrict__ bias, int N, float* __restrict__ outp)
{
    int n = (blockIdx.x * 256 + threadIdx.x) >> 6;
    int lane = threadIdx.x & 63;
    if (n >= N) return;
    int rs = row[n], re = row[n + 1];
    float adv = ad[n];
    float shift = lrelu(as[n] + adv);
    float dsum = 0.f;
    for (int j = rs; j < re; j += 64) {
        int jj = j + lane;
        bool v = jj < re;
        int s = adj[v ? jj : rs];
        float e = lrelu(as[s] + adv);
        float p = __expf(e - shift);
        dsum += v ? p : 0.f;
    }
    #pragma unroll
    for (int off = 1; off < 64; off <<= 1) dsum += __shfl_xor(dsum, off, 64);
    float denom = 1.f + dsum;
    float acc = hw[(size_t)n * 64 + lane];
    for (int j = rs; j < re; j += 4) {
        bool v1 = j + 1 < re, v2 = j + 2 < re, v3 = j + 3 < re;
        int s0 = adj[j];
        int s1 = v1 ? adj[j + 1] : s0;
        int s2 = v2 ? adj[j + 2] : s0;
        int s3 = v3 ? adj[j + 3] : s0;
        float e0 = lrelu(as[s0] + adv);
        float e1 = lrelu(as[s1] + adv);
        float e2 = lrelu(as[s2] + adv);
        float e3 = lrelu(as[s3] + adv);
        float w0 = __expf(e0 - shift);
        float w1 = v1 ? __expf(e1 - shift) : 0.f;
        float w2 = v2 ? __expf(e2 - shift) : 0.f;
        float w3 = v3 ? __expf(e3 - shift) : 0.f;
        acc = fmaf(w0, hw[(size_t)s0 * 64 + lane], acc);
        acc = fmaf(w1, hw[(size_t)s1 * 64 + lane], acc);
        acc = fmaf(w2, hw[(size_t)s2 * 64 + lane], acc);
        acc = fmaf(w3, hw[(size_t)s3 * 64 + lane], acc);
    }
    float o = acc / denom + bias[lane];
    outp[(size_t)n * 64 + lane] = eluf(o);
}

extern "C" void kernel_launch(void* const* d_in, const int* in_sizes, int n_in,
                              void* d_out, int out_size, void* d_ws, size_t ws_size,
                              hipStream_t stream)
{
    const float* x   = (const float*)d_in[0];
    const int*   ei  = (const int*)d_in[1];
    const float* W0  = (const float*)d_in[2];
    const float* aS0 = (const float*)d_in[3];
    const float* aD0 = (const float*)d_in[4];
    const float* b0  = (const float*)d_in[5];
    const float* W1  = (const float*)d_in[6];
    const float* aS1 = (const float*)d_in[7];
    const float* aD1 = (const float*)d_in[8];
    const float* b1  = (const float*)d_in[9];

    const int N = in_sizes[0] / 128;
    const int E = in_sizes[1] / 2;
    const int* srcp = ei;
    const int* dstp = ei + E;

    const int NB  = (N + 1023) >> 10;
    const int cap = E / NB + 4096;

    char* ws = (char*)d_ws;
    size_t off = 0;
    auto alloc = [&](size_t bytes) -> size_t {
        size_t o = off;
        off = (o + bytes + 255) & ~(size_t)255;
        return o;
    };
    float* B1  = (float*)(ws + alloc((size_t)N * 64 * 4));      // xW0
    // B2 (hw for layer1) overlays bucketBuf (dead after kP2; B2 written after)
    size_t b2Bytes = (size_t)N * 64 * 4;
    size_t bkBytes = (size_t)NB * cap * 4;
    char*  region  = ws + alloc(b2Bytes > bkBytes ? b2Bytes : bkBytes);
    float*    B2        = (float*)region;
    unsigned* bucketBuf = (unsigned*)region;
    float* as0 = (float*)(ws + alloc((size_t)N * 8 * 4));
    float* ad0 = (float*)(ws + alloc((size_t)N * 8 * 4));
    float* as1 = (float*)(ws + alloc((size_t)N * 4));
    float* ad1 = (float*)(ws + alloc((size_t)N * 4));
    int*   row = (int*)(ws + alloc((size_t)(N + 1) * 4));
    int*   adj = (int*)(ws + alloc((size_t)E * 4));
    int*  gcur = (int*)(ws + alloc((size_t)NB * 4));

    const int tfBlocks = (N + 63) / 64;
    const int p1Blocks = 1024;
    const int perBlock = (E + p1Blocks - 1) / p1Blocks;

    hipMemsetAsync(gcur, 0, (size_t)NB * 4, stream);
    kP1<<<tfBlocks + p1Blocks, 512, 0, stream>>>(
        x, W0, aS0, aD0, N, B1, as0, ad0, tfBlocks,
        srcp, dstp, E, p1Blocks, perBlock, bucketBuf, gcur, NB, cap);
    kP2<<<NB, 256, 0, stream>>>(bucketBuf, gcur, NB, cap, N, row, adj);

    const int agBlocks = (N + 3) / 4;
    k_agg8_tf1<<<agBlocks, 256, 0, stream>>>(B1, as0, ad0, row, adj, b0,
                                             W1, aS1, aD1, N, B2, as1, ad1);
    k_agg1<<<agBlocks, 256, 0, stream>>>(B2, as1, ad1, row, adj, b1, N, (float*)d_out);
}

// Round 6
// 508.229 us; speedup vs baseline: 1.0998x; 1.0998x over previous
//
#include <hip/hip_runtime.h>
#include <math.h>

// GAT 2-layer fp32.
// R6: agg kernels restructured — per-8-edge chunk, 64 lanes compute all 8x8
//     edge-head weights once; gather phase pulls w/src via shfl (no recompute,
//     no LDS); 8 independent gathers per chunk, 2 acc chains.

#define CAPS 32
#define STRIDE 33
#define NBMAX 128

__device__ __forceinline__ float lrelu(float v) { return v >= 0.f ? v : 0.2f * v; }
__device__ __forceinline__ float eluf(float v)  { return v > 0.f ? v : expm1f(v); }

// ---------------- transform body: 8 waves/block, 8 nodes/wave, lane = col ----
template<int K, int HEADS>
__device__ __forceinline__ void tf_body8(
    int tfb, const float* __restrict__ xin, const float* __restrict__ W,
    const float* __restrict__ attS, const float* __restrict__ attD,
    int N, float* __restrict__ xw, float* __restrict__ as, float* __restrict__ ad,
    float* Wl)
{
    const float4* Wv = (const float4*)W;
    float4* Wlv = (float4*)Wl;
    for (int i = threadIdx.x; i < K * 16; i += 512) Wlv[i] = Wv[i];
    __syncthreads();
    int wave = threadIdx.x >> 6;
    int lane = threadIdx.x & 63;
    int n0 = tfb * 64 + wave * 8;
    if (n0 >= N) return;
    int cnt = min(8, N - n0);
    const float4* xp[8];
    #pragma unroll
    for (int j = 0; j < 8; j++)
        xp[j] = (const float4*)(xin + (size_t)(n0 + (j < cnt ? j : 0)) * K);
    float acc[8] = {0.f,0.f,0.f,0.f,0.f,0.f,0.f,0.f};
    #pragma unroll 2
    for (int k4 = 0; k4 < K / 4; k4++) {
        float4 xv[8];
        #pragma unroll
        for (int j = 0; j < 8; j++) xv[j] = xp[j][k4];
        int kb = k4 * 256 + lane;
        float w0 = Wl[kb], w1 = Wl[kb + 64], w2 = Wl[kb + 128], w3 = Wl[kb + 192];
        #pragma unroll
        for (int j = 0; j < 8; j++) {
            acc[j] = fmaf(xv[j].x, w0, acc[j]);
            acc[j] = fmaf(xv[j].y, w1, acc[j]);
            acc[j] = fmaf(xv[j].z, w2, acc[j]);
            acc[j] = fmaf(xv[j].w, w3, acc[j]);
        }
    }
    float aSl = attS[lane], aDl = attD[lane];
    #pragma unroll
    for (int j = 0; j < 8; j++) {
        if (j < cnt) {
            int n = n0 + j;
            xw[(size_t)n * 64 + lane] = acc[j];
            float ps = acc[j] * aSl, pd = acc[j] * aDl;
            if (HEADS == 8) {
                ps += __shfl_xor(ps, 1, 64); pd += __shfl_xor(pd, 1, 64);
                ps += __shfl_xor(ps, 2, 64); pd += __shfl_xor(pd, 2, 64);
                ps += __shfl_xor(ps, 4, 64); pd += __shfl_xor(pd, 4, 64);
                if ((lane & 7) == 0) {
                    as[(size_t)n * 8 + (lane >> 3)] = ps;
                    ad[(size_t)n * 8 + (lane >> 3)] = pd;
                }
            } else {
                #pragma unroll
                for (int off = 1; off < 64; off <<= 1) {
                    ps += __shfl_xor(ps, off, 64);
                    pd += __shfl_xor(pd, off, 64);
                }
                if (lane == 0) { as[n] = ps; ad[n] = pd; }
            }
        }
    }
}

// ---------------- fused: phase1 binning || tf0 ----------------
__global__ __launch_bounds__(512, 4) void kP1(
    const float* __restrict__ x, const float* __restrict__ W0,
    const float* __restrict__ aS, const float* __restrict__ aD,
    int N, float* __restrict__ xw, float* __restrict__ as, float* __restrict__ ad,
    int tfBlocks,
    const int* __restrict__ src, const int* __restrict__ dst, int E,
    int p1Blocks, int perBlock,
    unsigned* __restrict__ bucketBuf, int* __restrict__ gcur, int NB, int cap)
{
    __shared__ __align__(16) char smem[128 * 64 * 4];
    int b = blockIdx.x;
    int T = tfBlocks + p1Blocks;
    int lo = (int)((long long)b * tfBlocks / T);
    int hi = (int)((long long)(b + 1) * tfBlocks / T);
    if (hi > lo) {
        tf_body8<128, 8>(lo, x, W0, aS, aD, N, xw, as, ad, (float*)smem);
    } else {
        int pb = b - hi;
        unsigned* stage = (unsigned*)smem;
        int* scnt = (int*)(smem + NBMAX * STRIDE * 4);
        int tid = threadIdx.x;
        for (int i = tid; i < NB; i += 512) scnt[i] = 0;
        __syncthreads();
        int e0 = pb * perBlock, e1 = min(E, e0 + perBlock);
        for (int base = e0; base < e1; base += 512) {
            int i = base + tid;
            if (i < e1) {
                int d = dst[i], s = src[i];
                int bk = d >> 10;
                unsigned rec = ((unsigned)(d & 1023) << 22) | (unsigned)s;
                int pos = atomicAdd(&scnt[bk], 1);
                if (pos < CAPS) {
                    stage[bk * STRIDE + pos] = rec;
                } else {
                    int g = atomicAdd(&gcur[bk], 1);
                    bucketBuf[(size_t)bk * cap + g] = rec;
                }
            }
            __syncthreads();
            if (tid < NB) {
                int n = min(scnt[tid], CAPS);
                int g16 = n & ~15;
                if (g16) {
                    int gb = atomicAdd(&gcur[tid], g16);
                    unsigned* gp = &bucketBuf[(size_t)tid * cap + gb];
                    for (int j = 0; j < g16; j++) gp[j] = stage[tid * STRIDE + j];
                    for (int j = 0; j < n - g16; j++)
                        stage[tid * STRIDE + j] = stage[tid * STRIDE + g16 + j];
                    scnt[tid] = n - g16;
                } else {
                    scnt[tid] = n;
                }
            }
            __syncthreads();
        }
        if (tid < NB) {
            int n = scnt[tid];
            if (n > 0) {
                int gb = atomicAdd(&gcur[tid], n);
                unsigned* gp = &bucketBuf[(size_t)tid * cap + gb];
                for (int j = 0; j < n; j++) gp[j] = stage[tid * STRIDE + j];
            }
        }
    }
}

// ---------------- phase2: per-bucket CSR build ----------------
__global__ __launch_bounds__(256) void kP2(
    const unsigned* __restrict__ bucketBuf, const int* __restrict__ gcur,
    int NB, int cap, int N, int* __restrict__ row, int* __restrict__ adj)
{
    __shared__ int deg[1024];
    __shared__ int curl[1024];
    __shared__ int sc[256];
    int b = blockIdx.x, tid = threadIdx.x;
    int lo = b << 10;
    int hi = min(N, lo + 1024);
    int cnt = hi - lo;
    int size = min(gcur[b], cap);
    sc[tid] = (tid < b) ? gcur[tid] : 0;
    __syncthreads();
    for (int off = 128; off > 0; off >>= 1) {
        if (tid < off) sc[tid] += sc[tid + off];
        __syncthreads();
    }
    int bbase = sc[0];
    __syncthreads();
    for (int i = tid; i < 1024; i += 256) deg[i] = 0;
    __syncthreads();
    const unsigned* buf = bucketBuf + (size_t)b * cap;
    for (int e = tid; e < size; e += 256) atomicAdd(&deg[buf[e] >> 22], 1);
    __syncthreads();
    int dv[4]; int s = 0;
    #pragma unroll
    for (int j = 0; j < 4; j++) { dv[j] = deg[tid * 4 + j]; s += dv[j]; }
    sc[tid] = s; __syncthreads();
    for (int off = 1; off < 256; off <<= 1) {
        int xv = (tid >= off) ? sc[tid - off] : 0;
        __syncthreads();
        sc[tid] += xv;
        __syncthreads();
    }
    int o = (tid ? sc[tid - 1] : 0);
    #pragma unroll
    for (int j = 0; j < 4; j++) {
        int loc = tid * 4 + j;
        curl[loc] = o;
        if (loc < cnt) row[lo + loc] = bbase + o;
        o += dv[j];
    }
    if (b == NB - 1 && tid == 0) row[N] = bbase + size;
    __syncthreads();
    for (int e = tid; e < size; e += 256) {
        unsigned r = buf[e];
        int l = r >> 22;
        int p = atomicAdd(&curl[l], 1);
        adj[bbase + p] = (int)(r & 0x3FFFFF);
    }
}

// ---------------- layer0 aggregation + fused layer1 transform ----------------
__global__ __launch_bounds__(256) void k_agg8_tf1(
    const float* __restrict__ xw, const float* __restrict__ as, const float* __restrict__ ad,
    const int* __restrict__ row, const int* __restrict__ adj,
    const float* __restrict__ bias, const float* __restrict__ W1,
    const float* __restrict__ aS1, const float* __restrict__ aD1,
    int N, float* __restrict__ hw, float* __restrict__ as1, float* __restrict__ ad1)
{
    __shared__ float Wl[64 * 64];
    {
        const float4* Wv = (const float4*)W1;
        float4* Wlv = (float4*)Wl;
        for (int i = threadIdx.x; i < 1024; i += 256) Wlv[i] = Wv[i];
    }
    __syncthreads();
    int n = (blockIdx.x * 256 + threadIdx.x) >> 6;
    int lane = threadIdx.x & 63;
    if (n >= N) return;
    int rs = row[n], re = row[n + 1];
    int hh = lane & 7;       // head (weight phase)
    int e8 = lane >> 3;      // edge-in-chunk (weight phase)
    int hb = lane >> 3;      // head (gather phase, lane = col)
    float adv = ad[(size_t)n * 8 + hh];
    float shift = lrelu(as[(size_t)n * 8 + hh] + adv);
    float acc = xw[(size_t)n * 64 + lane];   // self edge, w = 1
    float acc2 = 0.f;
    float dsum = 0.f;
    int j = rs;
    for (; j + 8 <= re; j += 8) {
        int s = adj[j + e8];
        float e = lrelu(as[(size_t)s * 8 + hh] + adv);
        float w = __expf(e - shift);
        dsum += w;
        #pragma unroll
        for (int t = 0; t < 8; t += 2) {
            float we0 = __shfl(w, t * 8 + hb, 64);
            int   se0 = __shfl(s, t * 8, 64);
            float we1 = __shfl(w, t * 8 + 8 + hb, 64);
            int   se1 = __shfl(s, t * 8 + 8, 64);
            acc  = fmaf(we0, xw[(size_t)se0 * 64 + lane], acc);
            acc2 = fmaf(we1, xw[(size_t)se1 * 64 + lane], acc2);
        }
    }
    int rem = re - j;
    if (rem > 0) {
        int jj = j + e8;
        bool v = jj < re;
        int s = adj[v ? jj : rs];
        float e = lrelu(as[(size_t)s * 8 + hh] + adv);
        float w = v ? __expf(e - shift) : 0.f;
        dsum += w;
        for (int t = 0; t < rem; t++) {   // rem is wave-uniform
            float we = __shfl(w, t * 8 + hb, 64);
            int   se = __shfl(s, t * 8, 64);
            acc = fmaf(we, xw[(size_t)se * 64 + lane], acc);
        }
    }
    acc += acc2;
    dsum += __shfl_xor(dsum, 8, 64);
    dsum += __shfl_xor(dsum, 16, 64);
    dsum += __shfl_xor(dsum, 32, 64);
    float denom = 1.f + __shfl(dsum, hb, 64);  // lane hb holds head hb's sum
    float h = eluf(acc / denom + bias[lane]);
    // ---- fused tf1 ----
    float a1 = 0.f;
    #pragma unroll 16
    for (int k = 0; k < 64; k++) {
        float hk = __shfl(h, k, 64);
        a1 = fmaf(hk, Wl[k * 64 + lane], a1);
    }
    hw[(size_t)n * 64 + lane] = a1;
    float ps = a1 * aS1[lane], pd = a1 * aD1[lane];
    #pragma unroll
    for (int off = 1; off < 64; off <<= 1) {
        ps += __shfl_xor(ps, off, 64);
        pd += __shfl_xor(pd, off, 64);
    }
    if (lane == 0) { as1[n] = ps; ad1[n] = pd; }
}

// ---------------- layer1 aggregation ----------------
__global__ __launch_bounds__(256) void k_agg1(
    const float* __restrict__ hw, const float* __restrict__ as, const float* __restrict__ ad,
    const int* __restrict__ row, const int* __restrict__ adj,
    const float* __restrict__ bias, int N, float* __restrict__ outp)
{
    int n = (blockIdx.x * 256 + threadIdx.x) >> 6;
    int lane = threadIdx.x & 63;
    if (n >= N) return;
    int rs = row[n], re = row[n + 1];
    int e8 = lane >> 3;
    float adv = ad[n];
    float shift = lrelu(as[n] + adv);
    float acc = hw[(size_t)n * 64 + lane];
    float acc2 = 0.f;
    float dsum = 0.f;
    int j = rs;
    for (; j + 8 <= re; j += 8) {
        int s = adj[j + e8];               // 8 distinct, each read by 8 lanes
        float e = lrelu(as[s] + adv);
        float w = __expf(e - shift);
        dsum += w;
        #pragma unroll
        for (int t = 0; t < 8; t += 2) {
            float we0 = __shfl(w, t * 8, 64);
            int   se0 = __shfl(s, t * 8, 64);
            float we1 = __shfl(w, t * 8 + 8, 64);
            int   se1 = __shfl(s, t * 8 + 8, 64);
            acc  = fmaf(we0, hw[(size_t)se0 * 64 + lane], acc);
            acc2 = fmaf(we1, hw[(size_t)se1 * 64 + lane], acc2);
        }
    }
    int rem = re - j;
    if (rem > 0) {
        int jj = j + e8;
        bool v = jj < re;
        int s = adj[v ? jj : rs];
        float e = lrelu(as[s] + adv);
        float w = v ? __expf(e - shift) : 0.f;
        dsum += w;
        for (int t = 0; t < rem; t++) {
            float we = __shfl(w, t * 8, 64);
            int   se = __shfl(s, t * 8, 64);
            acc = fmaf(we, hw[(size_t)se * 64 + lane], acc);
        }
    }
    acc += acc2;
    dsum += __shfl_xor(dsum, 8, 64);
    dsum += __shfl_xor(dsum, 16, 64);
    dsum += __shfl_xor(dsum, 32, 64);
    float denom = 1.f + dsum;
    float o = acc / denom + bias[lane];
    outp[(size_t)n * 64 + lane] = eluf(o);
}

extern "C" void kernel_launch(void* const* d_in, const int* in_sizes, int n_in,
                              void* d_out, int out_size, void* d_ws, size_t ws_size,
                              hipStream_t stream)
{
    const float* x   = (const float*)d_in[0];
    const int*   ei  = (const int*)d_in[1];
    const float* W0  = (const float*)d_in[2];
    const float* aS0 = (const float*)d_in[3];
    const float* aD0 = (const float*)d_in[4];
    const float* b0  = (const float*)d_in[5];
    const float* W1  = (const float*)d_in[6];
    const float* aS1 = (const float*)d_in[7];
    const float* aD1 = (const float*)d_in[8];
    const float* b1  = (const float*)d_in[9];

    const int N = in_sizes[0] / 128;
    const int E = in_sizes[1] / 2;
    const int* srcp = ei;
    const int* dstp = ei + E;

    const int NB  = (N + 1023) >> 10;
    const int cap = E / NB + 4096;

    char* ws = (char*)d_ws;
    size_t off = 0;
    auto alloc = [&](size_t bytes) -> size_t {
        size_t o = off;
        off = (o + bytes + 255) & ~(size_t)255;
        return o;
    };
    float* B1  = (float*)(ws + alloc((size_t)N * 64 * 4));      // xW0
    size_t b2Bytes = (size_t)N * 64 * 4;
    size_t bkBytes = (size_t)NB * cap * 4;
    char*  region  = ws + alloc(b2Bytes > bkBytes ? b2Bytes : bkBytes);
    float*    B2        = (float*)region;    // hw overlays bucketBuf
    unsigned* bucketBuf = (unsigned*)region;
    float* as0 = (float*)(ws + alloc((size_t)N * 8 * 4));
    float* ad0 = (float*)(ws + alloc((size_t)N * 8 * 4));
    float* as1 = (float*)(ws + alloc((size_t)N * 4));
    float* ad1 = (float*)(ws + alloc((size_t)N * 4));
    int*   row = (int*)(ws + alloc((size_t)(N + 1) * 4));
    int*   adj = (int*)(ws + alloc((size_t)E * 4));
    int*  gcur = (int*)(ws + alloc((size_t)NB * 4));

    const int tfBlocks = (N + 63) / 64;
    const int p1Blocks = 1024;
    const int perBlock = (E + p1Blocks - 1) / p1Blocks;

    hipMemsetAsync(gcur, 0, (size_t)NB * 4, stream);
    kP1<<<tfBlocks + p1Blocks, 512, 0, stream>>>(
        x, W0, aS0, aD0, N, B1, as0, ad0, tfBlocks,
        srcp, dstp, E, p1Blocks, perBlock, bucketBuf, gcur, NB, cap);
    kP2<<<NB, 256, 0, stream>>>(bucketBuf, gcur, NB, cap, N, row, adj);

    const int agBlocks = (N + 3) / 4;
    k_agg8_tf1<<<agBlocks, 256, 0, stream>>>(B1, as0, ad0, row, adj, b0,
                                             W1, aS1, aD1, N, B2, as1, ad1);
    k_agg1<<<agBlocks, 256, 0, stream>>>(B2, as1, ad1, row, adj, b1, N, (float*)d_out);
}